// Round 10
// baseline (139.242 us; speedup 1.0000x reference)
//
#include <hip/hip_runtime.h>

// Problem constants (from reference)
#define N_NODES 2048
#define C_CH    128
#define NIRR    9
#define E_EL    10
// dslot mapping: 0 -> l0 (d=0), 1..3 -> l1 (d=0..2)

// Symmetrized coupling tables, role-major so each wave (one role r = ds)
// scalar-loads a contiguous slice:
//   us3: [r(4)][s3(165)][k(4)]   = 2640 floats
//   us2: [r(4)][s2(45)][k(3)]    =  540
//   us1: [r(4)][p(9)][k(2)]      =   72
#define NS3 165
#define NS2 45
#define US3_FLOATS (NS3 * 16)   // 2640
#define US2_FLOATS (NS2 * 12)   //  540
#define US1_FLOATS (9 * 8)      //   72

// Compile-time index tables for the flattened symmetric triple loop.
struct Tab {
    unsigned char pairP[NS2], pairQ[NS2];
    unsigned char triPair[NS3], triI[NS3];
};
constexpr Tab makeTab() {
    Tab t{};
    int s2 = 0, s3 = 0;
    for (int p = 0; p < 9; p++)
        for (int q = p; q < 9; q++) {
            t.pairP[s2] = (unsigned char)p;
            t.pairQ[s2] = (unsigned char)q;
            for (int i = q; i < 9; i++) {
                t.triPair[s3] = (unsigned char)s2;
                t.triI[s3] = (unsigned char)i;
                s3++;
            }
            s2++;
        }
    return t;
}
constexpr Tab TAB = makeTab();

// Symmetrize u3/u2/u1 over index-permutation orbits (monomial x_p x_q x_i is
// symmetric, so only sorted index tuples matter). 3252 floats total.
__global__ __launch_bounds__(256) void build_sym_kernel(
    const float* __restrict__ u3_l0, const float* __restrict__ u2_l0, const float* __restrict__ u1_l0,
    const float* __restrict__ u3_l1, const float* __restrict__ u2_l1, const float* __restrict__ u1_l1,
    float* __restrict__ us3, float* __restrict__ us2, float* __restrict__ us1)
{
    int t = blockIdx.x * 256 + threadIdx.x;
    if (t < US3_FLOATS) {
        int s = t >> 4, dk = t & 15, ds = dk >> 2, k = dk & 3;
        int pp = 0, qq = 0, ii = 0, cntr = 0;
        for (int p = 0; p < 9; p++)
            for (int q = p; q < 9; q++)
                for (int i = q; i < 9; i++) {
                    if (cntr == s) { pp = p; qq = q; ii = i; }
                    cntr++;
                }
        const float* u = (ds == 0) ? u3_l0 : (u3_l1 + (ds - 1) * 2916);
        int perm[6][3] = {{pp,qq,ii},{pp,ii,qq},{qq,pp,ii},{qq,ii,pp},{ii,pp,qq},{ii,qq,pp}};
        float acc = 0.f;
        #pragma unroll
        for (int j = 0; j < 6; j++)
            acc += u[((perm[j][0] * 9 + perm[j][1]) * 9 + perm[j][2]) * 4 + k];
        float mult = (pp == qq && qq == ii) ? 6.f : ((pp == qq || qq == ii) ? 2.f : 1.f);
        us3[ds * (NS3 * 4) + s * 4 + k] = acc / mult;
    } else if (t < US3_FLOATS + US2_FLOATS) {
        int t2 = t - US3_FLOATS;
        int s = t2 / 12, dk = t2 % 12, ds = dk / 3, k = dk % 3;
        int pp = 0, qq = 0, cntr = 0;
        for (int p = 0; p < 9; p++)
            for (int q = p; q < 9; q++) {
                if (cntr == s) { pp = p; qq = q; }
                cntr++;
            }
        const float* u = (ds == 0) ? u2_l0 : (u2_l1 + (ds - 1) * 243);
        float acc = u[(pp * 9 + qq) * 3 + k] + u[(qq * 9 + pp) * 3 + k];
        us2[ds * (NS2 * 3) + s * 3 + k] = (pp == qq) ? acc * 0.5f : acc;
    } else if (t < US3_FLOATS + US2_FLOATS + US1_FLOATS) {
        int t1 = t - US3_FLOATS - US2_FLOATS;
        int p = t1 >> 3, dk = t1 & 7, ds = dk >> 1, k = dk & 1;
        const float* u = (ds == 0) ? u1_l0 : (u1_l1 + (ds - 1) * 18);
        us1[ds * 18 + p * 2 + k] = u[p * 2 + k];
    }
}

// Fused contraction + o3.Linear + skip. TWO nodes per block, 2 nodes/thread.
// Block = 512 = 128 c x 4 roles; role r computes dslot r for both nodes.
// The wave-uniform table s_loads and the epilogue lw loads are node-invariant,
// so 2 nodes/thread amortizes both 2x (this was the R8 bottleneck: ~17 us/CU
// of L1 traffic + lgkm waits, both per-wave costs).
// NOTE: needs >=100 VGPR headroom; never bound min-waves above 4 here
// (R5's (256,8) capped VGPRs at 64 with 45+ live values -> spill -> 14x).
__global__ __launch_bounds__(512, 4) void fused_kernel(
    const float* __restrict__ x, const float* __restrict__ y,
    const float* __restrict__ us3, const float* __restrict__ us2, const float* __restrict__ us1,
    const float* __restrict__ w3_l0, const float* __restrict__ w2_l0, const float* __restrict__ w1_l0,
    const float* __restrict__ w3_l1, const float* __restrict__ w2_l1, const float* __restrict__ w1_l1,
    const float* __restrict__ lw0, const float* __restrict__ lw1,
    const float* __restrict__ sc, float* __restrict__ out)
{
    __shared__ float fs[2][4][132];   // [node][dslot][c]
    int tid = threadIdx.x;
    int c = tid & 127;
    int r = __builtin_amdgcn_readfirstlane(tid >> 7);   // role == dslot, wave-uniform
    int b0 = blockIdx.x * 2;

    int e0 = 0, e1 = 0;
    #pragma unroll
    for (int k = 1; k < E_EL; k++) {
        if (y[b0 * E_EL + k] > 0.5f) e0 = k;
        if (y[(b0 + 1) * E_EL + k] > 0.5f) e1 = k;
    }
    e0 = __builtin_amdgcn_readfirstlane(e0);
    e1 = __builtin_amdgcn_readfirstlane(e1);

    float xv0[9], xv1[9];
    {
        const float* xp0 = x + ((size_t)b0 * C_CH + c) * NIRR;
        const float* xp1 = x + ((size_t)(b0 + 1) * C_CH + c) * NIRR;
        #pragma unroll
        for (int i = 0; i < 9; i++) { xv0[i] = xp0[i]; xv1[i] = xp1[i]; }
    }

    const float* t3 = us3 + r * (NS3 * 4);
    const float* t2 = us2 + r * (NS2 * 3);
    const float* t1 = us1 + r * 18;

    float G3a[4] = {0.f, 0.f, 0.f, 0.f}, G3b[4] = {0.f, 0.f, 0.f, 0.f};
    float G2a[3] = {0.f, 0.f, 0.f},      G2b[3] = {0.f, 0.f, 0.f};
    float G1a[2] = {0.f, 0.f},           G1b[2] = {0.f, 0.f};

    #pragma unroll
    for (int p = 0; p < 9; p++) {
        float u0 = t1[p * 2 + 0], u1 = t1[p * 2 + 1];
        G1a[0] += u0 * xv0[p]; G1a[1] += u1 * xv0[p];
        G1b[0] += u0 * xv1[p]; G1b[1] += u1 * xv1[p];
    }

    float pq0 = 0.f, pq1 = 0.f;
    #pragma unroll
    for (int s = 0; s < NS3; s++) {
        const int pi = TAB.triPair[s];
        if (s == 0 || TAB.triPair[s] != TAB.triPair[s - 1]) {
            pq0 = xv0[TAB.pairP[pi]] * xv0[TAB.pairQ[pi]];
            pq1 = xv1[TAB.pairP[pi]] * xv1[TAB.pairQ[pi]];
            float v0 = t2[pi * 3 + 0], v1 = t2[pi * 3 + 1], v2 = t2[pi * 3 + 2];
            G2a[0] += v0 * pq0; G2a[1] += v1 * pq0; G2a[2] += v2 * pq0;
            G2b[0] += v0 * pq1; G2b[1] += v1 * pq1; G2b[2] += v2 * pq1;
        }
        float X0 = pq0 * xv0[TAB.triI[s]];
        float X1 = pq1 * xv1[TAB.triI[s]];
        float u0 = t3[s * 4 + 0], u1 = t3[s * 4 + 1], u2 = t3[s * 4 + 2], u3 = t3[s * 4 + 3];
        G3a[0] += u0 * X0; G3a[1] += u1 * X0; G3a[2] += u2 * X0; G3a[3] += u3 * X0;
        G3b[0] += u0 * X1; G3b[1] += u1 * X1; G3b[2] += u2 * X1; G3b[3] += u3 * X1;
    }

    // element weights (lane c): w3 (E,4,C), w2 (E,3,C), w1 (E,2,C)
    const float* W3 = (r == 0) ? w3_l0 : w3_l1;
    const float* W2 = (r == 0) ? w2_l0 : w2_l1;
    const float* W1 = (r == 0) ? w1_l0 : w1_l1;
    {
        float acc0 = 0.f, acc1 = 0.f;
        #pragma unroll
        for (int k = 0; k < 4; k++) {
            acc0 += W3[(e0 * 4 + k) * 128 + c] * G3a[k];
            acc1 += W3[(e1 * 4 + k) * 128 + c] * G3b[k];
        }
        #pragma unroll
        for (int k = 0; k < 3; k++) {
            acc0 += W2[(e0 * 3 + k) * 128 + c] * G2a[k];
            acc1 += W2[(e1 * 3 + k) * 128 + c] * G2b[k];
        }
        #pragma unroll
        for (int k = 0; k < 2; k++) {
            acc0 += W1[(e0 * 2 + k) * 128 + c] * G1a[k];
            acc1 += W1[(e1 * 2 + k) * 128 + c] * G1b[k];
        }
        fs[0][r][c] = acc0;
        fs[1][r][c] = acc1;
    }
    __syncthreads();

    // o3.Linear: 512 threads <-> 512 output columns, each done for BOTH nodes
    // (W column loads amortized 2x).
    //   tid < 128: col = tid (l0 block, weights lw0, fs[n][0])
    //   else: u = tid-128, m = u>>7, j = u&127 -> col = 128 + 3j + m,
    //         weights lw1 (coalesced in j), fs[n][1+m]
    int sel, j, col;
    const float* W;
    if (tid < 128) { sel = 0; j = tid; col = tid; W = lw0; }
    else {
        int u = tid - 128;
        int m = u >> 7;
        j = u & 127;
        sel = 1 + m;
        col = 128 + 3 * j + m;
        W = lw1;
    }
    sel = __builtin_amdgcn_readfirstlane(sel);

    float a0 = 0.f, a1 = 0.f;
    #pragma unroll 8
    for (int ib = 0; ib < 32; ib++) {
        float4 f0 = *(const float4*)&fs[0][sel][4 * ib];
        float4 f1 = *(const float4*)&fs[1][sel][4 * ib];
        int i0 = 4 * ib;
        float wa = W[(i0 + 0) * 128 + j];
        float wb = W[(i0 + 1) * 128 + j];
        float wc = W[(i0 + 2) * 128 + j];
        float wd = W[(i0 + 3) * 128 + j];
        a0 += f0.x * wa + f0.y * wb + f0.z * wc + f0.w * wd;
        a1 += f1.x * wa + f1.y * wb + f1.z * wc + f1.w * wd;
    }

    const float inv_sqrt_c = 0.08838834764831845f;  // 1/sqrt(128)
    size_t oi0 = (size_t)b0 * 512 + col;
    size_t oi1 = (size_t)(b0 + 1) * 512 + col;
    out[oi0] = a0 * inv_sqrt_c + sc[oi0];
    out[oi1] = a1 * inv_sqrt_c + sc[oi1];
}

extern "C" void kernel_launch(void* const* d_in, const int* in_sizes, int n_in,
                              void* d_out, int out_size, void* d_ws, size_t ws_size,
                              hipStream_t stream) {
    const float* x     = (const float*)d_in[0];
    const float* y     = (const float*)d_in[1];
    const float* sc    = (const float*)d_in[2];
    const float* u3_l0 = (const float*)d_in[3];
    const float* u2_l0 = (const float*)d_in[4];
    const float* u1_l0 = (const float*)d_in[5];
    const float* w3_l0 = (const float*)d_in[6];
    const float* w2_l0 = (const float*)d_in[7];
    const float* w1_l0 = (const float*)d_in[8];
    const float* u3_l1 = (const float*)d_in[9];
    const float* u2_l1 = (const float*)d_in[10];
    const float* u1_l1 = (const float*)d_in[11];
    const float* w3_l1 = (const float*)d_in[12];
    const float* w2_l1 = (const float*)d_in[13];
    const float* w1_l1 = (const float*)d_in[14];
    const float* lw0   = (const float*)d_in[15];
    const float* lw1   = (const float*)d_in[16];
    float* out = (float*)d_out;

    // Workspace layout (floats): us3 | us2 | us1
    float* us3 = (float*)d_ws;
    float* us2 = us3 + US3_FLOATS;
    float* us1 = us2 + US2_FLOATS;

    build_sym_kernel<<<13, 256, 0, stream>>>(
        u3_l0, u2_l0, u1_l0, u3_l1, u2_l1, u1_l1, us3, us2, us1);
    fused_kernel<<<N_NODES / 2, 512, 0, stream>>>(
        x, y, us3, us2, us1,
        w3_l0, w2_l0, w1_l0, w3_l1, w2_l1, w1_l1,
        lw0, lw1, sc, out);
}